// Round 1
// baseline (11066.871 us; speedup 1.0000x reference)
//
#include <hip/hip_runtime.h>

#define Ndim 256
#define Fdim 64
#define Bn   8

// ---------------------------------------------------------------------------
// S0: transpose L2 -> L2T[l][z][w]  (so stage-3 A-operand loads are coalesced)
// ---------------------------------------------------------------------------
__global__ __launch_bounds__(256) void k_transpose_l2(const float* __restrict__ L2,
                                                      float* __restrict__ L2T) {
  __shared__ float tile[32][33];
  const int l = blockIdx.z;
  const int w0 = blockIdx.x * 32;
  const int z0 = blockIdx.y * 32;
  const float* src = L2 + (size_t)l * Ndim * Ndim;
  float* dst = L2T + (size_t)l * Ndim * Ndim;
  for (int i = threadIdx.y; i < 32; i += 8)
    tile[i][threadIdx.x] = src[(size_t)(w0 + i) * Ndim + z0 + threadIdx.x];
  __syncthreads();
  for (int i = threadIdx.y; i < 32; i += 8)
    dst[(size_t)(z0 + i) * Ndim + w0 + threadIdx.x] = tile[threadIdx.x][i];
}

// ---------------------------------------------------------------------------
// S1: A[b,u,w,f] = sum_v L1k[u,v] * H[b,v,w,f]   (GEMM M=256, N=16384, K=256)
// grid: (16384/64, 256/64, B), block 256, 4x4 per thread, BK=16
// ---------------------------------------------------------------------------
__global__ __launch_bounds__(256) void k_gemm_s1(const float* __restrict__ L1k,
                                                 const float* __restrict__ H,
                                                 float* __restrict__ A) {
  const int b = blockIdx.z;
  const int n0 = blockIdx.x * 64;
  const int u0 = blockIdx.y * 64;
  const float* Hb = H + (size_t)b * Ndim * Ndim * Fdim;
  float* Cb = A + (size_t)b * Ndim * Ndim * Fdim;
  __shared__ float As[64][16];
  __shared__ float Bs[16][64];
  const int t = threadIdx.x;
  const int tx = t & 15, ty = t >> 4;
  float acc[4][4] = {};
  for (int kt = 0; kt < Ndim; kt += 16) {
    {
      int r = t >> 2, c = (t & 3) << 2;
      *reinterpret_cast<float4*>(&As[r][c]) =
          *reinterpret_cast<const float4*>(&L1k[(size_t)(u0 + r) * Ndim + kt + c]);
    }
    {
      int r = t >> 4, c = (t & 15) << 2;
      *reinterpret_cast<float4*>(&Bs[r][c]) =
          *reinterpret_cast<const float4*>(&Hb[(size_t)(kt + r) * (Ndim * Fdim) + n0 + c]);
    }
    __syncthreads();
#pragma unroll
    for (int kk = 0; kk < 16; ++kk) {
      float a[4], bb[4];
#pragma unroll
      for (int i = 0; i < 4; ++i) a[i] = As[ty * 4 + i][kk];
#pragma unroll
      for (int j = 0; j < 4; ++j) bb[j] = Bs[kk][tx * 4 + j];
#pragma unroll
      for (int i = 0; i < 4; ++i)
#pragma unroll
        for (int j = 0; j < 4; ++j) acc[i][j] += a[i] * bb[j];
    }
    __syncthreads();
  }
#pragma unroll
  for (int i = 0; i < 4; ++i) {
    float4 v = {acc[i][0], acc[i][1], acc[i][2], acc[i][3]};
    *reinterpret_cast<float4*>(&Cb[(size_t)(u0 + ty * 4 + i) * (Ndim * Fdim) + n0 + tx * 4]) = v;
  }
}

// ---------------------------------------------------------------------------
// S2: P[l][row, o] (+)= sum_f A[row, f] * W[k, l0+l, f, o]   row = (b,u,w)
// block: 256 threads, 16 rows; W staged in LDS
// ---------------------------------------------------------------------------
__global__ __launch_bounds__(256) void k_wproj(const float* __restrict__ A,
                                               const float* __restrict__ Wk,  // + k*3*64*64
                                               float* __restrict__ P,
                                               int numL, int l0, int accum) {
  __shared__ float Ws[3][64][64];
  __shared__ float Asm[16][64];
  const int t = threadIdx.x;
  for (int l = 0; l < numL; ++l)
    for (int i = t; i < 64 * 64; i += 256)
      Ws[l][i >> 6][i & 63] = Wk[(size_t)(l0 + l) * 64 * 64 + i];
  const size_t row0 = (size_t)blockIdx.x * 16;
  for (int i = t; i < 16 * 64; i += 256) Asm[i >> 6][i & 63] = A[row0 * 64 + i];
  __syncthreads();
  const int o = t & 63;
  const int rsub = t >> 6;
  const size_t elemsA = (size_t)Bn * Ndim * Ndim * Fdim;
  for (int l = 0; l < numL; ++l) {
    float* Pl = P + (size_t)l * elemsA;
    for (int rp = 0; rp < 4; ++rp) {
      const int rl = rp * 4 + rsub;
      float acc = 0.f;
#pragma unroll
      for (int f = 0; f < 64; ++f) acc += Asm[rl][f] * Ws[l][f][o];
      const size_t idx = (row0 + rl) * 64 + o;
      if (accum) Pl[idx] += acc; else Pl[idx] = acc;
    }
  }
}

// ---------------------------------------------------------------------------
// S3: out[bu, z, o] (+)= sum_l sum_w L2T[l0+l][z,w] * P[l][bu,w,o]
// grid: (256/64 z-tiles, 2048 bu), block 256, 4x4 per thread
// finalize: out = relu(out + bias)
// ---------------------------------------------------------------------------
__global__ __launch_bounds__(256) void k_l2apply(const float* __restrict__ L2T,
                                                 const float* __restrict__ P,
                                                 const float* __restrict__ bias,
                                                 float* __restrict__ out,
                                                 int numL, int l0, int accum, int finalize) {
  const int bu = blockIdx.y;
  const int z0 = blockIdx.x * 64;
  __shared__ float As[64][16];
  __shared__ float Bs[16][64];
  const int t = threadIdx.x;
  const int tx = t & 15, ty = t >> 4;
  const size_t elemsA = (size_t)Bn * Ndim * Ndim * Fdim;
  float acc[4][4] = {};
  for (int l = 0; l < numL; ++l) {
    const float* Az = L2T + (size_t)(l0 + l) * Ndim * Ndim;
    const float* Pb = P + (size_t)l * elemsA + (size_t)bu * Ndim * Fdim;
    for (int kt = 0; kt < Ndim; kt += 16) {
      {
        int r = t >> 2, c = (t & 3) << 2;
        *reinterpret_cast<float4*>(&As[r][c]) =
            *reinterpret_cast<const float4*>(&Az[(size_t)(z0 + r) * Ndim + kt + c]);
      }
      {
        int r = t >> 4, c = (t & 15) << 2;
        *reinterpret_cast<float4*>(&Bs[r][c]) =
            *reinterpret_cast<const float4*>(&Pb[(size_t)(kt + r) * 64 + c]);
      }
      __syncthreads();
#pragma unroll
      for (int kk = 0; kk < 16; ++kk) {
        float a[4], bb[4];
#pragma unroll
        for (int i = 0; i < 4; ++i) a[i] = As[ty * 4 + i][kk];
#pragma unroll
        for (int j = 0; j < 4; ++j) bb[j] = Bs[kk][tx * 4 + j];
#pragma unroll
        for (int i = 0; i < 4; ++i)
#pragma unroll
          for (int j = 0; j < 4; ++j) acc[i][j] += a[i] * bb[j];
      }
      __syncthreads();
    }
  }
#pragma unroll
  for (int i = 0; i < 4; ++i) {
    const int z = z0 + ty * 4 + i;
    const size_t idx = ((size_t)bu * Ndim + z) * 64 + tx * 4;
    float4 v = {acc[i][0], acc[i][1], acc[i][2], acc[i][3]};
    if (accum) {
      float4 old = *reinterpret_cast<const float4*>(&out[idx]);
      v.x += old.x; v.y += old.y; v.z += old.z; v.w += old.w;
    }
    if (finalize) {
      v.x = fmaxf(v.x + bias[tx * 4 + 0], 0.f);
      v.y = fmaxf(v.y + bias[tx * 4 + 1], 0.f);
      v.z = fmaxf(v.z + bias[tx * 4 + 2], 0.f);
      v.w = fmaxf(v.w + bias[tx * 4 + 3], 0.f);
    }
    *reinterpret_cast<float4*>(&out[idx]) = v;
  }
}

__global__ __launch_bounds__(256) void k_finalize(float* __restrict__ out,
                                                  const float* __restrict__ bias, size_t n) {
  for (size_t i = (size_t)blockIdx.x * blockDim.x + threadIdx.x; i < n;
       i += (size_t)gridDim.x * blockDim.x)
    out[i] = fmaxf(out[i] + bias[i & 63], 0.f);
}

// ---------------------------------------------------------------------------
extern "C" void kernel_launch(void* const* d_in, const int* in_sizes, int n_in,
                              void* d_out, int out_size, void* d_ws, size_t ws_size,
                              hipStream_t stream) {
  const float* H    = (const float*)d_in[0];
  const float* L1   = (const float*)d_in[1];
  const float* L2   = (const float*)d_in[2];
  const float* Wt   = (const float*)d_in[3];
  const float* bias = (const float*)d_in[4];
  float* out = (float*)d_out;

  const size_t elemsA = (size_t)Bn * Ndim * Ndim * Fdim;  // 33,554,432
  const size_t szA = elemsA * sizeof(float);              // 128 MiB
  char* ws = (char*)d_ws;
  float* L2T  = (float*)ws;                 // 768 KiB (reserve 1 MiB)
  float* bufA = (float*)(ws + (1 << 20));
  float* bufP = (float*)(ws + (1 << 20) + szA);

  const bool path512 = ws_size >= (1ull << 20) + 4 * szA;  // A_k + P(all l)
  const bool path256 = ws_size >= (1ull << 20) + 2 * szA;  // A_k + P_kl

  k_transpose_l2<<<dim3(8, 8, 3), dim3(32, 8), 0, stream>>>(L2, L2T);

  if (path512) {
    for (int k = 0; k < 3; ++k) {
      k_gemm_s1<<<dim3(256, 4, Bn), 256, 0, stream>>>(L1 + (size_t)k * Ndim * Ndim, H, bufA);
      k_wproj<<<32768, 256, 0, stream>>>(bufA, Wt + (size_t)k * 3 * 64 * 64, bufP, 3, 0, k > 0);
    }
    k_l2apply<<<dim3(4, 2048), 256, 0, stream>>>(L2T, bufP, bias, out, 3, 0, 0, 1);
  } else if (path256) {
    hipMemsetAsync(out, 0, (size_t)out_size * sizeof(float), stream);
    for (int k = 0; k < 3; ++k) {
      k_gemm_s1<<<dim3(256, 4, Bn), 256, 0, stream>>>(L1 + (size_t)k * Ndim * Ndim, H, bufA);
      for (int l = 0; l < 3; ++l) {
        k_wproj<<<32768, 256, 0, stream>>>(bufA, Wt + (size_t)k * 3 * 64 * 64, bufP, 1, l, 0);
        k_l2apply<<<dim3(4, 2048), 256, 0, stream>>>(L2T, bufP, bias, out, 1, l, 1, 0);
      }
    }
    k_finalize<<<2048, 256, 0, stream>>>(out, bias, elemsA);
  }
  // else: ws too small for any path — intentional no-op (diagnostic: bench will
  // show absmax == max|ref| ≈ 44, distinguishing "ws too small" from a crash).
}

// Round 2
// 366.508 us; speedup vs baseline: 30.1954x; 30.1954x over previous
//
#include <hip/hip_runtime.h>

typedef __attribute__((ext_vector_type(8))) short s16x8;
typedef __attribute__((ext_vector_type(4))) float f32x4;

#define MFMA16 __builtin_amdgcn_mfma_f32_16x16x32_bf16

__device__ __forceinline__ short f2bf(float x) {
  union { float f; unsigned u; } c; c.f = x;
  unsigned r = (c.u + 0x7fffu + ((c.u >> 16) & 1u)) >> 16;
  return (short)r;
}

__device__ __forceinline__ void gld16(const void* g, void* l) {
  __builtin_amdgcn_global_load_lds(
      (const __attribute__((address_space(1))) unsigned*)g,
      (__attribute__((address_space(3))) unsigned*)l, 16, 0, 0);
}

// ---------------------------------------------------------------------------
// Prep: bf16 tables.
// ---------------------------------------------------------------------------
__global__ __launch_bounds__(256) void k_cvt_l1(const float* __restrict__ L1,
                                                short* __restrict__ L1b) {
  int i = blockIdx.x * 256 + threadIdx.x;  // 3*256*256
  L1b[i] = f2bf(L1[i]);
}

// L2cat[z*768 + l*256 + w] = L2[l][w][z]
__global__ __launch_bounds__(256) void k_build_l2cat(const float* __restrict__ L2,
                                                     short* __restrict__ L2cat) {
  __shared__ float t[32][33];
  const int l = blockIdx.z, w0 = blockIdx.x * 32, z0 = blockIdx.y * 32;
  const int tx = threadIdx.x, ty = threadIdx.y;
  const float* src = L2 + (size_t)l * 65536;
  for (int i = ty; i < 32; i += 8) t[i][tx] = src[(size_t)(w0 + i) * 256 + z0 + tx];
  __syncthreads();
  for (int i = ty; i < 32; i += 8)
    L2cat[(size_t)(z0 + i) * 768 + l * 256 + w0 + tx] = f2bf(t[tx][i]);
}

// WT[(l*64+o)*192 + k*64+f] = W[k][l][f][o]
__global__ __launch_bounds__(256) void k_build_wt(const float* __restrict__ W,
                                                  short* __restrict__ WT) {
  for (int idx = threadIdx.x + blockIdx.x * 256; idx < 192 * 192; idx += 256 * gridDim.x) {
    int lo = idx / 192, kf = idx % 192;
    int l = lo >> 6, o = lo & 63, k = kf / 64, f = kf & 63;
    WT[idx] = f2bf(W[(((size_t)(k * 3 + l) * 64 + f) << 6) + o]);
  }
}

// HbT[bc][wf][v] = bf16(H[b0+bc][v][wf])
__global__ __launch_bounds__(256) void k_cvt_ht(const float* __restrict__ H,
                                                short* __restrict__ HbT, int b0) {
  __shared__ float t[32][33];
  const int bc = blockIdx.z;
  const int wf0 = blockIdx.x * 32, v0 = blockIdx.y * 32;
  const int tx = threadIdx.x, ty = threadIdx.y;
  const float* src = H + ((size_t)(b0 + bc) * 256 + v0) * 16384;
  for (int i = ty; i < 32; i += 8) t[i][tx] = src[(size_t)i * 16384 + wf0 + tx];
  __syncthreads();
  short* dst = HbT + ((size_t)bc * 16384 + wf0) * 256;
  for (int i = ty; i < 32; i += 8) dst[(size_t)i * 256 + v0 + tx] = f2bf(t[tx][i]);
}

// ---------------------------------------------------------------------------
// S1: A2[((bc*256+u)*256+w)*192 + k*64+f] = sum_v L1b[k][u][v] * HbT[bc][w*64+f][v]
// 128x128 tile, BK=32, 4 waves (2x2), global_load_lds staging.
// ---------------------------------------------------------------------------
__global__ __launch_bounds__(256) void k_s1(const short* __restrict__ L1b,
                                            const short* __restrict__ HbT,
                                            short* __restrict__ A2, int nb) {
  __shared__ __align__(16) short At[128 * 32];
  __shared__ __align__(16) short Bt[128 * 32];
  const int t = threadIdx.x, lane = t & 63, wid = t >> 6;
  const int n0 = blockIdx.x * 128;
  const int u0 = blockIdx.y * 128;
  const int kk = blockIdx.z / nb;
  const int bc = blockIdx.z % nb;
  const short* Ag = L1b + (size_t)kk * 65536;        // [u][v]
  const short* Bg = HbT + (size_t)bc * 16384 * 256;  // [n][v]
  const int wm = wid >> 1, wn = wid & 1;
  const int srow = lane >> 2, selem = (lane & 3) * 8;
  f32x4 acc[4][4] = {};
  for (int kt = 0; kt < 256; kt += 32) {
#pragma unroll
    for (int j = 0; j < 2; ++j) {
      const int rb = wid * 32 + j * 16;
      gld16(Ag + (size_t)(u0 + rb + srow) * 256 + kt + selem, (short*)At + (size_t)rb * 32);
      gld16(Bg + (size_t)(n0 + rb + srow) * 256 + kt + selem, (short*)Bt + (size_t)rb * 32);
    }
    __syncthreads();
    const int ar = lane & 15, ks = (lane >> 4) * 8;
    s16x8 a[4], b[4];
#pragma unroll
    for (int i = 0; i < 4; ++i) a[i] = *(const s16x8*)&At[(wm * 64 + i * 16 + ar) * 32 + ks];
#pragma unroll
    for (int j = 0; j < 4; ++j) b[j] = *(const s16x8*)&Bt[(wn * 64 + j * 16 + ar) * 32 + ks];
#pragma unroll
    for (int i = 0; i < 4; ++i)
#pragma unroll
      for (int j = 0; j < 4; ++j) acc[i][j] = MFMA16(a[i], b[j], acc[i][j], 0, 0, 0);
    __syncthreads();
  }
  const int cr = lane >> 4, cc = lane & 15;
#pragma unroll
  for (int i = 0; i < 4; ++i)
#pragma unroll
    for (int j = 0; j < 4; ++j) {
      const int ncol = n0 + wn * 64 + j * 16 + cc;
      const int w = ncol >> 6, f = ncol & 63;
#pragma unroll
      for (int r = 0; r < 4; ++r) {
        const int u = u0 + wm * 64 + i * 16 + cr * 4 + r;
        A2[(((size_t)bc * 256 + u) * 256 + w) * 192 + kk * 64 + f] = f2bf(acc[i][j][r]);
      }
    }
}

// ---------------------------------------------------------------------------
// S2: D[lo][w] = sum_kf WT[lo][kf] * A2[(R0+w)][kf];  PT[(bu*64+o)*768 + l*256+w] = D
// M=192(lo) x N=128(w), K=192; 4 waves split lo (48 rows each).
// ---------------------------------------------------------------------------
__global__ __launch_bounds__(256) void k_s2(const short* __restrict__ A2,
                                            const short* __restrict__ WT,
                                            short* __restrict__ PT) {
  __shared__ __align__(16) short Wt_[192 * 32];
  __shared__ __align__(16) short At[128 * 32];
  const int t = threadIdx.x, lane = t & 63, wid = t >> 6;
  const size_t R0 = (size_t)blockIdx.x * 128;
  const int srow = lane >> 2, selem = (lane & 3) * 8;
  f32x4 acc[3][8] = {};
  for (int kt = 0; kt < 192; kt += 32) {
#pragma unroll
    for (int j = 0; j < 3; ++j) {
      const int rb = wid * 48 + j * 16;
      gld16(WT + (size_t)(rb + srow) * 192 + kt + selem, (short*)Wt_ + (size_t)rb * 32);
    }
#pragma unroll
    for (int j = 0; j < 2; ++j) {
      const int rb = wid * 32 + j * 16;
      gld16(A2 + (R0 + rb + srow) * 192 + kt + selem, (short*)At + (size_t)rb * 32);
    }
    __syncthreads();
    const int ar = lane & 15, ks = (lane >> 4) * 8;
    s16x8 a[3], b[8];
#pragma unroll
    for (int i = 0; i < 3; ++i) a[i] = *(const s16x8*)&Wt_[(wid * 48 + i * 16 + ar) * 32 + ks];
#pragma unroll
    for (int j = 0; j < 8; ++j) b[j] = *(const s16x8*)&At[(j * 16 + ar) * 32 + ks];
#pragma unroll
    for (int i = 0; i < 3; ++i)
#pragma unroll
      for (int j = 0; j < 8; ++j) acc[i][j] = MFMA16(a[i], b[j], acc[i][j], 0, 0, 0);
    __syncthreads();
  }
  const int bu = (int)(R0 >> 8);
  const int wb = (int)(R0 & 255);
  const int cr = lane >> 4, cc = lane & 15;
#pragma unroll
  for (int i = 0; i < 3; ++i)
#pragma unroll
    for (int r = 0; r < 4; ++r) {
      const int lo = wid * 48 + i * 16 + cr * 4 + r;
      const int l = lo >> 6, o = lo & 63;
      const size_t base = ((size_t)bu * 64 + o) * 768 + l * 256 + wb;
#pragma unroll
      for (int j = 0; j < 8; ++j) PT[base + j * 16 + cc] = f2bf(acc[i][j][r]);
    }
}

// ---------------------------------------------------------------------------
// S3: out[b0+bu>>8][u][z][o] = relu( sum_kidx L2cat[z][kidx]*PT[bu][o][kidx] + bias[o] )
// M=256(z) x N=64(o), K=768; 4 waves split z (64 rows each).
// ---------------------------------------------------------------------------
__global__ __launch_bounds__(256) void k_s3(const short* __restrict__ L2cat,
                                            const short* __restrict__ PT,
                                            const float* __restrict__ bias,
                                            float* __restrict__ out, int b0) {
  __shared__ __align__(16) short At[256 * 32];
  __shared__ __align__(16) short Bt[64 * 32];
  const int t = threadIdx.x, lane = t & 63, wid = t >> 6;
  const int bul = blockIdx.x;
  const short* Bg = PT + (size_t)bul * 64 * 768;
  const int srow = lane >> 2, selem = (lane & 3) * 8;
  f32x4 acc[4][4] = {};
  for (int kt = 0; kt < 768; kt += 32) {
#pragma unroll
    for (int j = 0; j < 4; ++j) {
      const int rb = wid * 64 + j * 16;
      gld16(L2cat + (size_t)(rb + srow) * 768 + kt + selem, (short*)At + (size_t)rb * 32);
    }
    {
      const int rb = wid * 16;
      gld16(Bg + (size_t)(rb + srow) * 768 + kt + selem, (short*)Bt + (size_t)rb * 32);
    }
    __syncthreads();
    const int ar = lane & 15, ks = (lane >> 4) * 8;
    s16x8 a[4], b[4];
#pragma unroll
    for (int i = 0; i < 4; ++i) a[i] = *(const s16x8*)&At[(wid * 64 + i * 16 + ar) * 32 + ks];
#pragma unroll
    for (int j = 0; j < 4; ++j) b[j] = *(const s16x8*)&Bt[(j * 16 + ar) * 32 + ks];
#pragma unroll
    for (int i = 0; i < 4; ++i)
#pragma unroll
      for (int j = 0; j < 4; ++j) acc[i][j] = MFMA16(a[i], b[j], acc[i][j], 0, 0, 0);
    __syncthreads();
  }
  const int bg = b0 + (bul >> 8), u = bul & 255;
  float* og = out + ((size_t)bg * 256 + u) * 256 * 64;
  const int cr = lane >> 4, cc = lane & 15;
#pragma unroll
  for (int i = 0; i < 4; ++i)
#pragma unroll
    for (int j = 0; j < 4; ++j) {
      const int o = j * 16 + cc;
      const float bv = bias[o];
#pragma unroll
      for (int r = 0; r < 4; ++r) {
        const int z = wid * 64 + i * 16 + cr * 4 + r;
        og[(size_t)z * 64 + o] = fmaxf(acc[i][j][r] + bv, 0.f);
      }
    }
}

// ---------------------------------------------------------------------------
extern "C" void kernel_launch(void* const* d_in, const int* in_sizes, int n_in,
                              void* d_out, int out_size, void* d_ws, size_t ws_size,
                              hipStream_t stream) {
  const float* H    = (const float*)d_in[0];
  const float* L1   = (const float*)d_in[1];
  const float* L2   = (const float*)d_in[2];
  const float* W    = (const float*)d_in[3];
  const float* bias = (const float*)d_in[4];
  float* out = (float*)d_out;

  char* ws = (char*)d_ws;
  short* L1b   = (short*)ws;                  // 384 KB
  short* L2cat = (short*)(ws + (384 << 10));  // 384 KB
  short* WT    = (short*)(ws + (768 << 10));  // 72 KB
  char* data = ws + (4ull << 20);

  // per-batch: HbT 8 MiB + A2 24 MiB + PT 24 MiB = 56 MiB
  const size_t perb = 56ull << 20;
  size_t avail = (ws_size > (4ull << 20)) ? ws_size - (4ull << 20) : 0;
  int nb = 1;
  if (avail >= 8 * perb) nb = 8;
  else if (avail >= 4 * perb) nb = 4;
  else if (avail >= 2 * perb) nb = 2;

  short* HbT = (short*)data;
  short* A2  = (short*)(data + (size_t)nb * (8ull << 20));
  short* PT  = (short*)(data + (size_t)nb * (32ull << 20));

  k_cvt_l1<<<768, 256, 0, stream>>>(L1, L1b);
  k_build_l2cat<<<dim3(8, 8, 3), dim3(32, 8), 0, stream>>>(L2, L2cat);
  k_build_wt<<<36, 256, 0, stream>>>(W, WT);

  for (int b0 = 0; b0 < 8; b0 += nb) {
    k_cvt_ht<<<dim3(512, 8, nb), dim3(32, 8), 0, stream>>>(H, HbT, b0);
    k_s1<<<dim3(128, 2, 3 * nb), 256, 0, stream>>>(L1b, HbT, A2, nb);
    k_s2<<<nb * 512, 256, 0, stream>>>(A2, WT, PT);
    k_s3<<<nb * 256, 256, 0, stream>>>(L2cat, PT, bias, out, b0);
  }
}

// Round 3
// 363.443 us; speedup vs baseline: 30.4501x; 1.0084x over previous
//
#include <hip/hip_runtime.h>

typedef __attribute__((ext_vector_type(8))) short s16x8;
typedef __attribute__((ext_vector_type(4))) float f32x4;

#define MFMA16 __builtin_amdgcn_mfma_f32_16x16x32_bf16

__device__ __forceinline__ short f2bf(float x) {
  union { float f; unsigned u; } c; c.f = x;
  unsigned r = (c.u + 0x7fffu + ((c.u >> 16) & 1u)) >> 16;
  return (short)r;
}

__device__ __forceinline__ void gld16(const void* g, void* l) {
  __builtin_amdgcn_global_load_lds(
      (const __attribute__((address_space(1))) unsigned*)g,
      (__attribute__((address_space(3))) unsigned*)l, 16, 0, 0);
}

// Bank-conflict swizzle (both-sides involution, rule #21):
//   LDS rows are 32 shorts (64 B = four 16 B slots). Linear layout gives bank
//   base (row*16)%32 -> 8-way conflict on fragment reads. We permute the 16 B
//   slot with slot ^= (row>>1)&3 on BOTH the global source of global_load_lds
//   and the ds_read address. Subtile row bases are multiples of 16 and kt is a
//   multiple of 32, so the XOR term reduces to a per-lane constant:
//   stage: selem = ((lane&3) ^ ((lane>>3)&3)) * 8   (row = lane>>2)
//   read : koff  = ((lane>>4) ^ ((lane>>1)&3)) * 8  (row = ...+ (lane&15))
// Result: each wave64 ds_read_b128 hits every bank exactly twice (2-way = free).

// ---------------------------------------------------------------------------
// Prep: bf16 tables.
// ---------------------------------------------------------------------------
__global__ __launch_bounds__(256) void k_cvt_l1(const float* __restrict__ L1,
                                                short* __restrict__ L1b) {
  int i = blockIdx.x * 256 + threadIdx.x;  // 3*256*256
  L1b[i] = f2bf(L1[i]);
}

// L2cat[z*768 + l*256 + w] = L2[l][w][z]
__global__ __launch_bounds__(256) void k_build_l2cat(const float* __restrict__ L2,
                                                     short* __restrict__ L2cat) {
  __shared__ float t[32][33];
  const int l = blockIdx.z, w0 = blockIdx.x * 32, z0 = blockIdx.y * 32;
  const int tx = threadIdx.x, ty = threadIdx.y;
  const float* src = L2 + (size_t)l * 65536;
  for (int i = ty; i < 32; i += 8) t[i][tx] = src[(size_t)(w0 + i) * 256 + z0 + tx];
  __syncthreads();
  for (int i = ty; i < 32; i += 8)
    L2cat[(size_t)(z0 + i) * 768 + l * 256 + w0 + tx] = f2bf(t[tx][i]);
}

// WT[(l*64+o)*192 + k*64+f] = W[k][l][f][o]
__global__ __launch_bounds__(256) void k_build_wt(const float* __restrict__ W,
                                                  short* __restrict__ WT) {
  for (int idx = threadIdx.x + blockIdx.x * 256; idx < 192 * 192; idx += 256 * gridDim.x) {
    int lo = idx / 192, kf = idx % 192;
    int l = lo >> 6, o = lo & 63, k = kf / 64, f = kf & 63;
    WT[idx] = f2bf(W[(((size_t)(k * 3 + l) * 64 + f) << 6) + o]);
  }
}

// HbT[bc][wf][v] = bf16(H[b0+bc][v][wf])
__global__ __launch_bounds__(256) void k_cvt_ht(const float* __restrict__ H,
                                                short* __restrict__ HbT, int b0) {
  __shared__ float t[32][33];
  const int bc = blockIdx.z;
  const int wf0 = blockIdx.x * 32, v0 = blockIdx.y * 32;
  const int tx = threadIdx.x, ty = threadIdx.y;
  const float* src = H + ((size_t)(b0 + bc) * 256 + v0) * 16384;
  for (int i = ty; i < 32; i += 8) t[i][tx] = src[(size_t)i * 16384 + wf0 + tx];
  __syncthreads();
  short* dst = HbT + ((size_t)bc * 16384 + wf0) * 256;
  for (int i = ty; i < 32; i += 8) dst[(size_t)i * 256 + v0 + tx] = f2bf(t[tx][i]);
}

// ---------------------------------------------------------------------------
// S1: A2[((bc*256+u)*256+w)*192 + k*64+f] = sum_v L1b[k][u][v] * HbT[bc][w*64+f][v]
// 128x128 tile, BK=32, 4 waves (2x2), global_load_lds staging, swizzled LDS.
// ---------------------------------------------------------------------------
__global__ __launch_bounds__(256) void k_s1(const short* __restrict__ L1b,
                                            const short* __restrict__ HbT,
                                            short* __restrict__ A2, int nb) {
  __shared__ __align__(16) short At[128 * 32];
  __shared__ __align__(16) short Bt[128 * 32];
  const int t = threadIdx.x, lane = t & 63, wid = t >> 6;
  const int n0 = blockIdx.x * 128;
  const int u0 = blockIdx.y * 128;
  const int kk = blockIdx.z / nb;
  const int bc = blockIdx.z % nb;
  const short* Ag = L1b + (size_t)kk * 65536;        // [u][v]
  const short* Bg = HbT + (size_t)bc * 16384 * 256;  // [n][v]
  const int wm = wid >> 1, wn = wid & 1;
  const int srow = lane >> 2;
  const int selem = ((lane & 3) ^ ((lane >> 3) & 3)) * 8;
  const int koff = (((lane >> 4) ^ ((lane >> 1) & 3)) * 8);
  f32x4 acc[4][4] = {};
  for (int kt = 0; kt < 256; kt += 32) {
#pragma unroll
    for (int j = 0; j < 2; ++j) {
      const int rb = wid * 32 + j * 16;
      gld16(Ag + (size_t)(u0 + rb + srow) * 256 + kt + selem, (short*)At + (size_t)rb * 32);
      gld16(Bg + (size_t)(n0 + rb + srow) * 256 + kt + selem, (short*)Bt + (size_t)rb * 32);
    }
    __syncthreads();
    const int ar = lane & 15;
    s16x8 a[4], b[4];
#pragma unroll
    for (int i = 0; i < 4; ++i) a[i] = *(const s16x8*)&At[(wm * 64 + i * 16 + ar) * 32 + koff];
#pragma unroll
    for (int j = 0; j < 4; ++j) b[j] = *(const s16x8*)&Bt[(wn * 64 + j * 16 + ar) * 32 + koff];
#pragma unroll
    for (int i = 0; i < 4; ++i)
#pragma unroll
      for (int j = 0; j < 4; ++j) acc[i][j] = MFMA16(a[i], b[j], acc[i][j], 0, 0, 0);
    __syncthreads();
  }
  const int cr = lane >> 4, cc = lane & 15;
#pragma unroll
  for (int i = 0; i < 4; ++i)
#pragma unroll
    for (int j = 0; j < 4; ++j) {
      const int ncol = n0 + wn * 64 + j * 16 + cc;
      const int w = ncol >> 6, f = ncol & 63;
#pragma unroll
      for (int r = 0; r < 4; ++r) {
        const int u = u0 + wm * 64 + i * 16 + cr * 4 + r;
        A2[(((size_t)bc * 256 + u) * 256 + w) * 192 + kk * 64 + f] = f2bf(acc[i][j][r]);
      }
    }
}

// ---------------------------------------------------------------------------
// S2: D[lo][w] = sum_kf WT[lo][kf] * A2[(R0+w)][kf];  PT[(bu*64+o)*768 + l*256+w] = D
// M=192(lo) x N=128(w), K=192; 4 waves split lo (48 rows each). Swizzled LDS.
// ---------------------------------------------------------------------------
__global__ __launch_bounds__(256) void k_s2(const short* __restrict__ A2,
                                            const short* __restrict__ WT,
                                            short* __restrict__ PT) {
  __shared__ __align__(16) short Wt_[192 * 32];
  __shared__ __align__(16) short At[128 * 32];
  const int t = threadIdx.x, lane = t & 63, wid = t >> 6;
  const size_t R0 = (size_t)blockIdx.x * 128;
  const int srow = lane >> 2;
  const int selem = ((lane & 3) ^ ((lane >> 3) & 3)) * 8;
  const int koff = (((lane >> 4) ^ ((lane >> 1) & 3)) * 8);
  f32x4 acc[3][8] = {};
  for (int kt = 0; kt < 192; kt += 32) {
#pragma unroll
    for (int j = 0; j < 3; ++j) {
      const int rb = wid * 48 + j * 16;
      gld16(WT + (size_t)(rb + srow) * 192 + kt + selem, (short*)Wt_ + (size_t)rb * 32);
    }
#pragma unroll
    for (int j = 0; j < 2; ++j) {
      const int rb = wid * 32 + j * 16;
      gld16(A2 + (R0 + rb + srow) * 192 + kt + selem, (short*)At + (size_t)rb * 32);
    }
    __syncthreads();
    const int ar = lane & 15;
    s16x8 a[3], b[8];
#pragma unroll
    for (int i = 0; i < 3; ++i)
      a[i] = *(const s16x8*)&Wt_[(wid * 48 + i * 16 + ar) * 32 + koff];
#pragma unroll
    for (int j = 0; j < 8; ++j) b[j] = *(const s16x8*)&At[(j * 16 + ar) * 32 + koff];
#pragma unroll
    for (int i = 0; i < 3; ++i)
#pragma unroll
      for (int j = 0; j < 8; ++j) acc[i][j] = MFMA16(a[i], b[j], acc[i][j], 0, 0, 0);
    __syncthreads();
  }
  const int bu = (int)(R0 >> 8);
  const int wb = (int)(R0 & 255);
  const int cr = lane >> 4, cc = lane & 15;
#pragma unroll
  for (int i = 0; i < 3; ++i)
#pragma unroll
    for (int r = 0; r < 4; ++r) {
      const int lo = wid * 48 + i * 16 + cr * 4 + r;
      const int l = lo >> 6, o = lo & 63;
      const size_t base = ((size_t)bu * 64 + o) * 768 + l * 256 + wb;
#pragma unroll
      for (int j = 0; j < 8; ++j) PT[base + j * 16 + cc] = f2bf(acc[i][j][r]);
    }
}

// ---------------------------------------------------------------------------
// S3: out[b0+bu>>8][u][z][o] = relu( sum_kidx L2cat[z][kidx]*PT[bu][o][kidx] + bias[o] )
// M=256(z) x N=64(o), K=768; 4 waves split z (64 rows each). Swizzled LDS.
// ---------------------------------------------------------------------------
__global__ __launch_bounds__(256) void k_s3(const short* __restrict__ L2cat,
                                            const short* __restrict__ PT,
                                            const float* __restrict__ bias,
                                            float* __restrict__ out, int b0) {
  __shared__ __align__(16) short At[256 * 32];
  __shared__ __align__(16) short Bt[64 * 32];
  const int t = threadIdx.x, lane = t & 63, wid = t >> 6;
  const int bul = blockIdx.x;
  const short* Bg = PT + (size_t)bul * 64 * 768;
  const int srow = lane >> 2;
  const int selem = ((lane & 3) ^ ((lane >> 3) & 3)) * 8;
  const int koff = (((lane >> 4) ^ ((lane >> 1) & 3)) * 8);
  f32x4 acc[4][4] = {};
  for (int kt = 0; kt < 768; kt += 32) {
#pragma unroll
    for (int j = 0; j < 4; ++j) {
      const int rb = wid * 64 + j * 16;
      gld16(L2cat + (size_t)(rb + srow) * 768 + kt + selem, (short*)At + (size_t)rb * 32);
    }
    {
      const int rb = wid * 16;
      gld16(Bg + (size_t)(rb + srow) * 768 + kt + selem, (short*)Bt + (size_t)rb * 32);
    }
    __syncthreads();
    const int ar = lane & 15;
    s16x8 a[4], b[4];
#pragma unroll
    for (int i = 0; i < 4; ++i)
      a[i] = *(const s16x8*)&At[(wid * 64 + i * 16 + ar) * 32 + koff];
#pragma unroll
    for (int j = 0; j < 4; ++j) b[j] = *(const s16x8*)&Bt[(j * 16 + ar) * 32 + koff];
#pragma unroll
    for (int i = 0; i < 4; ++i)
#pragma unroll
      for (int j = 0; j < 4; ++j) acc[i][j] = MFMA16(a[i], b[j], acc[i][j], 0, 0, 0);
    __syncthreads();
  }
  const int bg = b0 + (bul >> 8), u = bul & 255;
  float* og = out + ((size_t)bg * 256 + u) * 256 * 64;
  const int cr = lane >> 4, cc = lane & 15;
#pragma unroll
  for (int i = 0; i < 4; ++i)
#pragma unroll
    for (int j = 0; j < 4; ++j) {
      const int o = j * 16 + cc;
      const float bv = bias[o];
#pragma unroll
      for (int r = 0; r < 4; ++r) {
        const int z = wid * 64 + i * 16 + cr * 4 + r;
        og[(size_t)z * 64 + o] = fmaxf(acc[i][j][r] + bv, 0.f);
      }
    }
}

// ---------------------------------------------------------------------------
extern "C" void kernel_launch(void* const* d_in, const int* in_sizes, int n_in,
                              void* d_out, int out_size, void* d_ws, size_t ws_size,
                              hipStream_t stream) {
  const float* H    = (const float*)d_in[0];
  const float* L1   = (const float*)d_in[1];
  const float* L2   = (const float*)d_in[2];
  const float* W    = (const float*)d_in[3];
  const float* bias = (const float*)d_in[4];
  float* out = (float*)d_out;

  char* ws = (char*)d_ws;
  short* L1b   = (short*)ws;                  // 384 KB
  short* L2cat = (short*)(ws + (384 << 10));  // 384 KB
  short* WT    = (short*)(ws + (768 << 10));  // 72 KB
  char* data = ws + (4ull << 20);

  // per-batch: HbT 8 MiB + A2 24 MiB + PT 24 MiB = 56 MiB
  const size_t perb = 56ull << 20;
  size_t avail = (ws_size > (4ull << 20)) ? ws_size - (4ull << 20) : 0;
  int nb = 1;
  if (avail >= 8 * perb) nb = 8;
  else if (avail >= 4 * perb) nb = 4;
  else if (avail >= 2 * perb) nb = 2;

  short* HbT = (short*)data;
  short* A2  = (short*)(data + (size_t)nb * (8ull << 20));
  short* PT  = (short*)(data + (size_t)nb * (32ull << 20));

  k_cvt_l1<<<768, 256, 0, stream>>>(L1, L1b);
  k_build_l2cat<<<dim3(8, 8, 3), dim3(32, 8), 0, stream>>>(L2, L2cat);
  k_build_wt<<<36, 256, 0, stream>>>(W, WT);

  for (int b0 = 0; b0 < 8; b0 += nb) {
    k_cvt_ht<<<dim3(512, 8, nb), dim3(32, 8), 0, stream>>>(H, HbT, b0);
    k_s1<<<dim3(128, 2, 3 * nb), 256, 0, stream>>>(L1b, HbT, A2, nb);
    k_s2<<<nb * 512, 256, 0, stream>>>(A2, WT, PT);
    k_s3<<<nb * 256, 256, 0, stream>>>(L2cat, PT, bias, out, b0);
  }
}

// Round 4
// 334.290 us; speedup vs baseline: 33.1056x; 1.0872x over previous
//
#include <hip/hip_runtime.h>

typedef __attribute__((ext_vector_type(8))) short s16x8;
typedef __attribute__((ext_vector_type(4))) float f32x4;

#define MFMA16 __builtin_amdgcn_mfma_f32_16x16x32_bf16

__device__ __forceinline__ short f2bf(float x) {
  union { float f; unsigned u; } c; c.f = x;
  unsigned r = (c.u + 0x7fffu + ((c.u >> 16) & 1u)) >> 16;
  return (short)r;
}

__device__ __forceinline__ void gld16(const void* g, void* l) {
  __builtin_amdgcn_global_load_lds(
      (const __attribute__((address_space(1))) unsigned*)g,
      (__attribute__((address_space(3))) unsigned*)l, 16, 0, 0);
}

// Swizzle notes:
//  BK=32 tiles (k_s1): rows 64 B; slot ^= row-parity bits (R3 scheme, verified
//  conflict-free). BK=64 tiles (k_s23): rows 128 B = 8 slots; s' = s ^ (row&7);
//  stage: selem = ((lane&7) ^ ((lane>>3)&7))*8 (row base mult of 8);
//  read: ko(kk) = ((kk*4 + (lane>>4)) ^ (lane&7))*8 (row base mult of 16).
//  P buffer [o][768]: row stride 1536 B; slot s = lw>>3, stored at s^(o&7) —
//  written from stage-2 acc (packed b32) and read as stage-3 B-frags with the
//  same involution; uniform 8-lanes-per-4-bank-group (conflict-free b128).

// ---------------------------------------------------------------------------
// Prep
// ---------------------------------------------------------------------------
__global__ __launch_bounds__(256) void k_cvt_l1(const float* __restrict__ L1,
                                                short* __restrict__ L1b) {
  int i = blockIdx.x * 256 + threadIdx.x;  // 3*256*256
  L1b[i] = f2bf(L1[i]);
}

// L2cat[z*768 + l*256 + w] = L2[l][w][z]
__global__ __launch_bounds__(256) void k_build_l2cat(const float* __restrict__ L2,
                                                     short* __restrict__ L2cat) {
  __shared__ float t[32][33];
  const int l = blockIdx.z, w0 = blockIdx.x * 32, z0 = blockIdx.y * 32;
  const int tx = threadIdx.x, ty = threadIdx.y;
  const float* src = L2 + (size_t)l * 65536;
  for (int i = ty; i < 32; i += 8) t[i][tx] = src[(size_t)(w0 + i) * 256 + z0 + tx];
  __syncthreads();
  for (int i = ty; i < 32; i += 8)
    L2cat[(size_t)(z0 + i) * 768 + l * 256 + w0 + tx] = f2bf(t[tx][i]);
}

// WT[(l*64+o)*192 + k*64+f] = W[k][l][f][o]
__global__ __launch_bounds__(256) void k_build_wt(const float* __restrict__ W,
                                                  short* __restrict__ WT) {
  for (int idx = threadIdx.x + blockIdx.x * 256; idx < 192 * 192; idx += 256 * gridDim.x) {
    int lo = idx / 192, kf = idx % 192;
    int l = lo >> 6, o = lo & 63, k = kf / 64, f = kf & 63;
    WT[idx] = f2bf(W[(((size_t)(k * 3 + l) * 64 + f) << 6) + o]);
  }
}

// HbT[bc][wf][v] = bf16(H[b0+bc][v][wf])
__global__ __launch_bounds__(256) void k_cvt_ht(const float* __restrict__ H,
                                                short* __restrict__ HbT, int b0) {
  __shared__ float t[32][33];
  const int bc = blockIdx.z;
  const int wf0 = blockIdx.x * 32, v0 = blockIdx.y * 32;
  const int tx = threadIdx.x, ty = threadIdx.y;
  const float* src = H + ((size_t)(b0 + bc) * 256 + v0) * 16384;
  for (int i = ty; i < 32; i += 8) t[i][tx] = src[(size_t)i * 16384 + wf0 + tx];
  __syncthreads();
  short* dst = HbT + ((size_t)bc * 16384 + wf0) * 256;
  for (int i = ty; i < 32; i += 8) dst[(size_t)i * 256 + v0 + tx] = f2bf(t[tx][i]);
}

// ---------------------------------------------------------------------------
// S1: A2[((bc*256+u)*256+w)*192 + k*64+f] = sum_v L1b[k][u][v] * HbT[bc][w*64+f][v]
// Grid reordered so the 6 sharers of each HbT B-tile (3 kk x 2 u0) are 128-640
// block-ids apart (same XCD, temporally co-resident) -> L2 hits instead of HBM.
// ---------------------------------------------------------------------------
__global__ __launch_bounds__(256) void k_s1(const short* __restrict__ L1b,
                                            const short* __restrict__ HbT,
                                            short* __restrict__ A2) {
  __shared__ __align__(16) short At[128 * 32];
  __shared__ __align__(16) short Bt[128 * 32];
  const int t = threadIdx.x, lane = t & 63, wid = t >> 6;
  const int n0 = blockIdx.x * 128;
  const int kk = blockIdx.y >> 1;
  const int u0 = (blockIdx.y & 1) * 128;
  const int bc = blockIdx.z;
  const short* Ag = L1b + (size_t)kk * 65536;        // [u][v]
  const short* Bg = HbT + (size_t)bc * 16384 * 256;  // [n][v]
  const int wm = wid >> 1, wn = wid & 1;
  const int srow = lane >> 2;
  const int selem = ((lane & 3) ^ ((lane >> 3) & 3)) * 8;
  const int koff = (((lane >> 4) ^ ((lane >> 1) & 3)) * 8);
  f32x4 acc[4][4] = {};
  for (int kt = 0; kt < 256; kt += 32) {
#pragma unroll
    for (int j = 0; j < 2; ++j) {
      const int rb = wid * 32 + j * 16;
      gld16(Ag + (size_t)(u0 + rb + srow) * 256 + kt + selem, (short*)At + (size_t)rb * 32);
      gld16(Bg + (size_t)(n0 + rb + srow) * 256 + kt + selem, (short*)Bt + (size_t)rb * 32);
    }
    __syncthreads();
    const int ar = lane & 15;
    s16x8 a[4], b[4];
#pragma unroll
    for (int i = 0; i < 4; ++i) a[i] = *(const s16x8*)&At[(wm * 64 + i * 16 + ar) * 32 + koff];
#pragma unroll
    for (int j = 0; j < 4; ++j) b[j] = *(const s16x8*)&Bt[(wn * 64 + j * 16 + ar) * 32 + koff];
#pragma unroll
    for (int i = 0; i < 4; ++i)
#pragma unroll
      for (int j = 0; j < 4; ++j) acc[i][j] = MFMA16(a[i], b[j], acc[i][j], 0, 0, 0);
    __syncthreads();
  }
  const int cr = lane >> 4, cc = lane & 15;
#pragma unroll
  for (int i = 0; i < 4; ++i)
#pragma unroll
    for (int j = 0; j < 4; ++j) {
      const int ncol = n0 + wn * 64 + j * 16 + cc;
      const int w = ncol >> 6, f = ncol & 63;
#pragma unroll
      for (int r = 0; r < 4; ++r) {
        const int u = u0 + wm * 64 + i * 16 + cr * 4 + r;
        A2[(((size_t)bc * 256 + u) * 256 + w) * 192 + kk * 64 + f] = f2bf(acc[i][j][r]);
      }
    }
}

// ---------------------------------------------------------------------------
// S2+S3 fused, one block per bu (512 threads, 8 waves, 152 KB LDS):
//  Phase 1: P[l][w][o] = sum_kf A2[bu][w][kf] * WT[l*64+o][kf]
//           (M=256 w, N=64 o per l, K=192, BK=64) -> P kept in LDS as
//           P[o][l*256+w] with slot-XOR swizzle.
//  Phase 2: out[bu][z][o] = relu(sum_lw L2cat[z][lw] * P[o][lw] + bias[o])
//           (M=256 z, N=64 o, K=768, BK=64), B-frags read from P directly.
// ---------------------------------------------------------------------------
__global__ __launch_bounds__(512) void k_s23(const short* __restrict__ A2,
                                             const short* __restrict__ WT,
                                             const short* __restrict__ L2cat,
                                             const float* __restrict__ bias,
                                             float* __restrict__ out, int b0) {
  __shared__ __align__(16) short P[64 * 768];   // 98304 B
  __shared__ __align__(16) short At[256 * 64];  // 32768 B
  __shared__ __align__(16) short Bs[192 * 64];  // 24576 B
  const int t = threadIdx.x, lane = t & 63, wid = t >> 6;
  const int bul = blockIdx.x;
  const int ar = lane & 15, cc = lane & 15, cr = lane >> 4;
  const int selem = ((lane & 7) ^ ((lane >> 3) & 7)) * 8;            // stage (shorts)
  const int ko0 = (((lane >> 4)) ^ (lane & 7)) * 8;                  // kk=0
  const int ko1 = ((4 + (lane >> 4)) ^ (lane & 7)) * 8;              // kk=1
  const int srow8 = lane >> 3;

  // ---- Phase 1 ----
  f32x4 acc[3][2][4] = {};
  const short* A2g = A2 + (size_t)bul * 256 * 192;
  for (int kt = 0; kt < 192; kt += 64) {
#pragma unroll
    for (int is = 0; is < 4; ++is) {
      const int rb = wid * 32 + is * 8;
      gld16(A2g + (size_t)(rb + srow8) * 192 + kt + selem, (short*)At + (size_t)rb * 64);
    }
#pragma unroll
    for (int is = 0; is < 3; ++is) {
      const int rb = wid * 24 + is * 8;
      gld16(WT + (size_t)(rb + srow8) * 192 + kt + selem, (short*)Bs + (size_t)rb * 64);
    }
    __syncthreads();
    s16x8 a0[2], a1[2];
#pragma unroll
    for (int i = 0; i < 2; ++i) {
      a0[i] = *(const s16x8*)&At[(wid * 32 + i * 16 + ar) * 64 + ko0];
      a1[i] = *(const s16x8*)&At[(wid * 32 + i * 16 + ar) * 64 + ko1];
    }
#pragma unroll
    for (int l = 0; l < 3; ++l)
#pragma unroll
      for (int j = 0; j < 4; ++j) {
        s16x8 b0v = *(const s16x8*)&Bs[(l * 64 + j * 16 + ar) * 64 + ko0];
        s16x8 b1v = *(const s16x8*)&Bs[(l * 64 + j * 16 + ar) * 64 + ko1];
#pragma unroll
        for (int i = 0; i < 2; ++i) {
          acc[l][i][j] = MFMA16(a0[i], b0v, acc[l][i][j], 0, 0, 0);
          acc[l][i][j] = MFMA16(a1[i], b1v, acc[l][i][j], 0, 0, 0);
        }
      }
    __syncthreads();
  }
  // acc -> P (packed b32 writes, swizzled slots)
#pragma unroll
  for (int l = 0; l < 3; ++l)
#pragma unroll
    for (int i = 0; i < 2; ++i)
#pragma unroll
      for (int j = 0; j < 4; ++j)
#pragma unroll
        for (int rp = 0; rp < 2; ++rp) {
          const int r = rp * 2;
          const int w = wid * 32 + i * 16 + cr * 4 + r;
          const int o = j * 16 + cc;
          const int lw = l * 256 + w;
          const int addr = o * 768 + ((lw >> 3) ^ (o & 7)) * 8 + (lw & 7);
          unsigned lo16 = (unsigned short)f2bf(acc[l][i][j][r]);
          unsigned hi16 = (unsigned short)f2bf(acc[l][i][j][r + 1]);
          *(unsigned*)&P[addr] = lo16 | (hi16 << 16);
        }
  __syncthreads();

  // ---- Phase 2 ----
  f32x4 acc2[2][4] = {};
  for (int kt = 0; kt < 768; kt += 64) {
#pragma unroll
    for (int is = 0; is < 4; ++is) {
      const int rb = wid * 32 + is * 8;
      gld16(L2cat + (size_t)(rb + srow8) * 768 + kt + selem, (short*)At + (size_t)rb * 64);
    }
    __syncthreads();
    s16x8 a0[2], a1[2];
#pragma unroll
    for (int i = 0; i < 2; ++i) {
      a0[i] = *(const s16x8*)&At[(wid * 32 + i * 16 + ar) * 64 + ko0];
      a1[i] = *(const s16x8*)&At[(wid * 32 + i * 16 + ar) * 64 + ko1];
    }
#pragma unroll
    for (int j = 0; j < 4; ++j) {
      s16x8 b0v = *(const s16x8*)&P[(j * 16 + ar) * 768 + kt + ko0];
      s16x8 b1v = *(const s16x8*)&P[(j * 16 + ar) * 768 + kt + ko1];
#pragma unroll
      for (int i = 0; i < 2; ++i) {
        acc2[i][j] = MFMA16(a0[i], b0v, acc2[i][j], 0, 0, 0);
        acc2[i][j] = MFMA16(a1[i], b1v, acc2[i][j], 0, 0, 0);
      }
    }
    __syncthreads();
  }
  // epilogue: bias + relu + store
  const int bu_g = b0 * 256 + bul;
  float* og = out + (size_t)bu_g * 256 * 64;
#pragma unroll
  for (int i = 0; i < 2; ++i)
#pragma unroll
    for (int j = 0; j < 4; ++j) {
      const float bv = bias[j * 16 + cc];
#pragma unroll
      for (int r = 0; r < 4; ++r) {
        const int z = wid * 32 + i * 16 + cr * 4 + r;
        og[(size_t)z * 64 + j * 16 + cc] = fmaxf(acc2[i][j][r] + bv, 0.f);
      }
    }
}

// ---------------------------------------------------------------------------
extern "C" void kernel_launch(void* const* d_in, const int* in_sizes, int n_in,
                              void* d_out, int out_size, void* d_ws, size_t ws_size,
                              hipStream_t stream) {
  const float* H    = (const float*)d_in[0];
  const float* L1   = (const float*)d_in[1];
  const float* L2   = (const float*)d_in[2];
  const float* W    = (const float*)d_in[3];
  const float* bias = (const float*)d_in[4];
  float* out = (float*)d_out;

  char* ws = (char*)d_ws;
  short* L1b   = (short*)ws;                  // 384 KB
  short* L2cat = (short*)(ws + (384 << 10));  // 384 KB
  short* WT    = (short*)(ws + (768 << 10));  // 72 KB
  char* data = ws + (4ull << 20);

  // per-batch: HbT 8 MiB + A2 24 MiB = 32 MiB
  const size_t perb = 32ull << 20;
  size_t avail = (ws_size > (4ull << 20)) ? ws_size - (4ull << 20) : 0;
  int nb = 1;
  if (avail >= 8 * perb) nb = 8;
  else if (avail >= 4 * perb) nb = 4;
  else if (avail >= 2 * perb) nb = 2;

  short* HbT = (short*)data;
  short* A2  = (short*)(data + (size_t)nb * (8ull << 20));

  k_cvt_l1<<<768, 256, 0, stream>>>(L1, L1b);
  k_build_l2cat<<<dim3(8, 8, 3), dim3(32, 8), 0, stream>>>(L2, L2cat);
  k_build_wt<<<36, 256, 0, stream>>>(W, WT);

  for (int b0 = 0; b0 < 8; b0 += nb) {
    k_cvt_ht<<<dim3(512, 8, nb), dim3(32, 8), 0, stream>>>(H, HbT, b0);
    k_s1<<<dim3(128, 6, nb), 256, 0, stream>>>(L1b, HbT, A2);
    k_s23<<<nb * 256, 512, 0, stream>>>(A2, WT, L2cat, bias, out, b0);
  }
}